// Round 1
// baseline (107.371 us; speedup 1.0000x reference)
//
#include <hip/hip_runtime.h>

#define SIZE 128

typedef short short8 __attribute__((ext_vector_type(8)));
typedef float f32x4 __attribute__((ext_vector_type(4)));

__device__ __forceinline__ unsigned short f2bf(float f) {
    unsigned int u = __float_as_uint(f);
    unsigned int r = u + 0x7FFFu + ((u >> 16) & 1u);
    return (unsigned short)(r >> 16);
}

// Build Gt[n][k] = gr[(n-k) & 127] in bf16, where gr = Re(ifft(b)).
// gr[m] = (1/128) * sum_j ( br[j]*cos(2*pi*j*m/128) - bi[j]*sin(2*pi*j*m/128) )
__global__ void build_gt(const float* __restrict__ br, const float* __restrict__ bi,
                         unsigned short* __restrict__ Gt) {
    __shared__ float gr[SIZE];
    const int t = threadIdx.x;  // 0..127
    double acc = 0.0;
    for (int j = 0; j < SIZE; ++j) {
        int p = (j * t) & 127;                       // exact periodic reduction
        double ang = (double)p * (3.14159265358979323846 / 64.0);  // 2*pi*p/128
        acc += (double)br[j] * cos(ang) - (double)bi[j] * sin(ang);
    }
    gr[t] = (float)(acc / 128.0);
    __syncthreads();
    for (int k = 0; k < SIZE; ++k) {
        Gt[t * SIZE + k] = f2bf(gr[(t - k) & 127]);
    }
}

// out[row][n] = sum_k h[row][k] * Gt[n][k] + x[row][n],  h = tanh(alpha*x)*w + bias
// Block: 256 threads (4 waves), 64-row M-tile. Wave w owns columns [32w, 32w+32).
__global__ __launch_bounds__(256) void fourier_main(
    const float* __restrict__ x, const float* __restrict__ alpha_p,
    const float* __restrict__ w, const float* __restrict__ bias,
    const unsigned short* __restrict__ Gt, float* __restrict__ out) {
    __shared__ unsigned short hA[64][136];  // bf16 h tile; +8 pad: stride 68 dwords = 4 mod 32 -> uniform banks on b128 frag reads
    __shared__ float xs[64][132];           // fp32 x tile for residual

    const int tid = threadIdx.x;
    const int lane = tid & 63;
    const int wid = tid >> 6;
    const long long blockRow = (long long)blockIdx.x * 64;

    const float alpha = alpha_p[0];
    const int n0 = (tid & 31) * 4;  // column group of this thread for staging
    const float4 w4 = *reinterpret_cast<const float4*>(&w[n0]);
    const float4 b4 = *reinterpret_cast<const float4*>(&bias[n0]);

    // ---- stage x (fp32) and h (bf16) into LDS, 8 passes x 1024 elements ----
#pragma unroll
    for (int p = 0; p < 8; ++p) {
        const int row = p * 8 + (tid >> 5);
        const float4 xv =
            *reinterpret_cast<const float4*>(&x[(blockRow + row) * SIZE + n0]);
        *reinterpret_cast<float4*>(&xs[row][n0]) = xv;
        ushort4 hq;
        hq.x = f2bf(tanhf(alpha * xv.x) * w4.x + b4.x);
        hq.y = f2bf(tanhf(alpha * xv.y) * w4.y + b4.y);
        hq.z = f2bf(tanhf(alpha * xv.z) * w4.z + b4.z);
        hq.w = f2bf(tanhf(alpha * xv.w) * w4.w + b4.w);
        *reinterpret_cast<ushort4*>(&hA[row][n0]) = hq;
    }

    // ---- B fragments (G matrix), from global (L2-resident, 32 KB) ----
    // B-frag lane map: col = lane&15, k-chunk = (lane>>4)*8 .. +7 (consistent with A-frag)
    short8 bfrag[2][4];
    const int colb = wid * 32;
#pragma unroll
    for (int nt = 0; nt < 2; ++nt) {
        const int col = colb + nt * 16 + (lane & 15);
#pragma unroll
        for (int kt = 0; kt < 4; ++kt) {
            bfrag[nt][kt] = *reinterpret_cast<const short8*>(
                &Gt[col * SIZE + kt * 32 + (lane >> 4) * 8]);
        }
    }

    __syncthreads();

    // ---- MFMA: 4 M-tiles x 2 N-tiles, K = 128 (4 k-steps of 32) ----
    f32x4 acc[4][2];
#pragma unroll
    for (int mt = 0; mt < 4; ++mt) {
        short8 af[4];
#pragma unroll
        for (int kt = 0; kt < 4; ++kt) {
            af[kt] = *reinterpret_cast<const short8*>(
                &hA[mt * 16 + (lane & 15)][kt * 32 + (lane >> 4) * 8]);
        }
#pragma unroll
        for (int nt = 0; nt < 2; ++nt) {
            f32x4 a = {0.f, 0.f, 0.f, 0.f};
#pragma unroll
            for (int kt = 0; kt < 4; ++kt) {
                a = __builtin_amdgcn_mfma_f32_16x16x32_bf16(af[kt], bfrag[nt][kt], a,
                                                            0, 0, 0);
            }
            acc[mt][nt] = a;
        }
    }

    // ---- epilogue: C/D map col = lane&15, row = (lane>>4)*4 + reg ----
#pragma unroll
    for (int mt = 0; mt < 4; ++mt) {
#pragma unroll
        for (int nt = 0; nt < 2; ++nt) {
            const int col = colb + nt * 16 + (lane & 15);
            const int r0 = mt * 16 + (lane >> 4) * 4;
#pragma unroll
            for (int q = 0; q < 4; ++q) {
                const int row = r0 + q;
                out[(blockRow + row) * SIZE + col] = acc[mt][nt][q] + xs[row][col];
            }
        }
    }
}

extern "C" void kernel_launch(void* const* d_in, const int* in_sizes, int n_in,
                              void* d_out, int out_size, void* d_ws, size_t ws_size,
                              hipStream_t stream) {
    const float* x = (const float*)d_in[0];
    const float* alpha = (const float*)d_in[1];
    const float* dyt_w = (const float*)d_in[2];
    const float* dyt_b = (const float*)d_in[3];
    // d_in[4] = a_real, d_in[5] = a_imag, d_in[8] = ffn_bias: dead code in reference
    const float* b_real = (const float*)d_in[6];
    const float* b_imag = (const float*)d_in[7];
    float* out = (float*)d_out;
    unsigned short* Gt = (unsigned short*)d_ws;  // 128*128 bf16 = 32 KB

    build_gt<<<1, 128, 0, stream>>>(b_real, b_imag, Gt);

    const int rows = out_size / SIZE;       // 32*8192 = 262144
    const int nblocks = rows / 64;          // 4096
    fourier_main<<<nblocks, 256, 0, stream>>>(x, alpha, dyt_w, dyt_b, Gt, out);
}

// Round 2
// 83.276 us; speedup vs baseline: 1.2893x; 1.2893x over previous
//
#include <hip/hip_runtime.h>

#define SIZE 128

typedef short short8 __attribute__((ext_vector_type(8)));
typedef float f32x4 __attribute__((ext_vector_type(4)));

__device__ __forceinline__ unsigned short f2bf(float f) {
    unsigned int u = __float_as_uint(f);
    unsigned int r = u + 0x7FFFu + ((u >> 16) & 1u);
    return (unsigned short)(r >> 16);
}

// Build Gt[n][k] = gr[(n-k) & 127] in bf16, where gr = Re(ifft(b)).
// gr[m] = (1/128) * sum_j ( br[j]*cos(2*pi*j*m/128) - bi[j]*sin(2*pi*j*m/128) )
// float + {cos,sin}pif on exact p/64 arguments: error ~1e-6, far below bf16 ulp.
__global__ void build_gt(const float* __restrict__ br, const float* __restrict__ bi,
                         unsigned short* __restrict__ Gt) {
    __shared__ float gr[SIZE];
    const int t = threadIdx.x;  // 0..127
    float acc = 0.0f;
    for (int j = 0; j < SIZE; ++j) {
        int p = (j * t) & 127;                 // exact periodic reduction
        float a = (float)p * (1.0f / 64.0f);   // angle in units of pi
        acc += br[j] * cospif(a) - bi[j] * sinpif(a);
    }
    gr[t] = acc * (1.0f / 128.0f);
    __syncthreads();
    for (int k = 0; k < SIZE; ++k) {
        Gt[t * SIZE + k] = f2bf(gr[(t - k) & 127]);
    }
}

// out[row][n] = sum_k h[row][k] * Gt[n][k] + x[row][n],  h = tanh(alpha*x)*w + bias
// Block: 256 threads (4 waves), 64-row M-tile. Wave w owns columns [32w, 32w+32).
// Residual x is RE-READ from global at the epilogue (L2-hot) instead of an LDS
// tile: LDS 51.2 KB -> 17.4 KB lifts blocks/CU from 3 to ~7.
__global__ __launch_bounds__(256, 6) void fourier_main(
    const float* __restrict__ x, const float* __restrict__ alpha_p,
    const float* __restrict__ w, const float* __restrict__ bias,
    const unsigned short* __restrict__ Gt, float* __restrict__ out) {
    __shared__ unsigned short hA[64][136];  // bf16 h tile; +8 pad breaks pow2 stride

    const int tid = threadIdx.x;
    const int lane = tid & 63;
    const int wid = tid >> 6;
    const long long blockRow = (long long)blockIdx.x * 64;

    const float alpha = alpha_p[0];
    const int n0 = (tid & 31) * 4;  // column group of this thread for staging
    const float4 w4 = *reinterpret_cast<const float4*>(&w[n0]);
    const float4 b4 = *reinterpret_cast<const float4*>(&bias[n0]);

    // ---- stage h (bf16) into LDS, 8 passes x 1024 elements ----
    // fast tanh: tanh(t) = 1 - 2/(1 + e^{2t}); e->inf handled (rcp(inf)=0)
#pragma unroll
    for (int p = 0; p < 8; ++p) {
        const int row = p * 8 + (tid >> 5);
        const float4 xv =
            *reinterpret_cast<const float4*>(&x[(blockRow + row) * SIZE + n0]);
        ushort4 hq;
        {
            float ax, th;
            ax = alpha * xv.x;
            th = 1.0f - __fdividef(2.0f, 1.0f + __expf(2.0f * ax));
            hq.x = f2bf(th * w4.x + b4.x);
            ax = alpha * xv.y;
            th = 1.0f - __fdividef(2.0f, 1.0f + __expf(2.0f * ax));
            hq.y = f2bf(th * w4.y + b4.y);
            ax = alpha * xv.z;
            th = 1.0f - __fdividef(2.0f, 1.0f + __expf(2.0f * ax));
            hq.z = f2bf(th * w4.z + b4.z);
            ax = alpha * xv.w;
            th = 1.0f - __fdividef(2.0f, 1.0f + __expf(2.0f * ax));
            hq.w = f2bf(th * w4.w + b4.w);
        }
        *reinterpret_cast<ushort4*>(&hA[row][n0]) = hq;
    }

    // ---- B fragments (G matrix), from global (L2-resident, 32 KB) ----
    // B-frag lane map: col = lane&15, k-chunk = (lane>>4)*8 (consistent with A-frag)
    short8 bfrag[2][4];
    const int colb = wid * 32;
#pragma unroll
    for (int nt = 0; nt < 2; ++nt) {
        const int col = colb + nt * 16 + (lane & 15);
#pragma unroll
        for (int kt = 0; kt < 4; ++kt) {
            bfrag[nt][kt] = *reinterpret_cast<const short8*>(
                &Gt[col * SIZE + kt * 32 + (lane >> 4) * 8]);
        }
    }

    __syncthreads();

    // ---- MFMA: 4 M-tiles x 2 N-tiles, K = 128 (4 k-steps of 32) ----
    f32x4 acc[4][2];
#pragma unroll
    for (int mt = 0; mt < 4; ++mt) {
        short8 af[4];
#pragma unroll
        for (int kt = 0; kt < 4; ++kt) {
            af[kt] = *reinterpret_cast<const short8*>(
                &hA[mt * 16 + (lane & 15)][kt * 32 + (lane >> 4) * 8]);
        }
#pragma unroll
        for (int nt = 0; nt < 2; ++nt) {
            f32x4 a = {0.f, 0.f, 0.f, 0.f};
#pragma unroll
            for (int kt = 0; kt < 4; ++kt) {
                a = __builtin_amdgcn_mfma_f32_16x16x32_bf16(af[kt], bfrag[nt][kt], a,
                                                            0, 0, 0);
            }
            acc[mt][nt] = a;
        }
    }

    // ---- epilogue: C/D map col = lane&15, row = (lane>>4)*4 + reg ----
    // residual x re-read from global: block tile is L2-hot (just staged from it)
#pragma unroll
    for (int mt = 0; mt < 4; ++mt) {
#pragma unroll
        for (int nt = 0; nt < 2; ++nt) {
            const int col = colb + nt * 16 + (lane & 15);
            const int r0 = mt * 16 + (lane >> 4) * 4;
#pragma unroll
            for (int q = 0; q < 4; ++q) {
                const long long gi = (blockRow + r0 + q) * SIZE + col;
                out[gi] = acc[mt][nt][q] + x[gi];
            }
        }
    }
}

extern "C" void kernel_launch(void* const* d_in, const int* in_sizes, int n_in,
                              void* d_out, int out_size, void* d_ws, size_t ws_size,
                              hipStream_t stream) {
    const float* x = (const float*)d_in[0];
    const float* alpha = (const float*)d_in[1];
    const float* dyt_w = (const float*)d_in[2];
    const float* dyt_b = (const float*)d_in[3];
    // d_in[4] = a_real, d_in[5] = a_imag, d_in[8] = ffn_bias: dead code in reference
    const float* b_real = (const float*)d_in[6];
    const float* b_imag = (const float*)d_in[7];
    float* out = (float*)d_out;
    unsigned short* Gt = (unsigned short*)d_ws;  // 128*128 bf16 = 32 KB

    build_gt<<<1, 128, 0, stream>>>(b_real, b_imag, Gt);

    const int rows = out_size / SIZE;       // 32*8192 = 262144
    const int nblocks = rows / 64;          // 4096
    fourier_main<<<nblocks, 256, 0, stream>>>(x, alpha, dyt_w, dyt_b, Gt, out);
}

// Round 3
// 73.480 us; speedup vs baseline: 1.4612x; 1.1333x over previous
//
#include <hip/hip_runtime.h>

#define SIZE 128

typedef short short8 __attribute__((ext_vector_type(8)));
typedef float f32x4 __attribute__((ext_vector_type(4)));

__device__ __forceinline__ unsigned short f2bf(float f) {
    unsigned int u = __float_as_uint(f);
    unsigned int r = u + 0x7FFFu + ((u >> 16) & 1u);
    return (unsigned short)(r >> 16);
}

// Build Gt[n][k] = gr[(n-k) & 127] in bf16, where gr = Re(ifft(b)).
__global__ void build_gt(const float* __restrict__ br, const float* __restrict__ bi,
                         unsigned short* __restrict__ Gt) {
    __shared__ float gr[SIZE];
    const int t = threadIdx.x;  // 0..127
    float acc = 0.0f;
    for (int j = 0; j < SIZE; ++j) {
        int p = (j * t) & 127;                 // exact periodic reduction
        float a = (float)p * (1.0f / 64.0f);   // angle in units of pi
        acc += br[j] * cospif(a) - bi[j] * sinpif(a);
    }
    gr[t] = acc * (1.0f / 128.0f);
    __syncthreads();
    for (int k = 0; k < SIZE; ++k) {
        Gt[t * SIZE + k] = f2bf(gr[(t - k) & 127]);
    }
}

// out[m][n] = sum_k h[m][k] * Gt[n][k] + x[m][n],  h = tanh(alpha*x)*w + bias
// 256 threads (4 waves), 64-row tile. Wave w owns columns [32w, 32w+32).
// SWAPPED mfma(G, h): C/D regs = 4 consecutive output COLS -> float4 stores,
// and per-thread (row,col) footprint is static, so x stays in registers
// from staging to residual add (no epilogue re-read, x fetched ONCE).
__global__ __launch_bounds__(256, 4) void fourier_main(
    const float* __restrict__ x, const float* __restrict__ alpha_p,
    const float* __restrict__ w, const float* __restrict__ bias,
    const unsigned short* __restrict__ Gt, float* __restrict__ out) {
    __shared__ unsigned short hA[64][136];  // bf16 h tile; +8 pad breaks pow2 stride

    const int tid = threadIdx.x;
    const int lane = tid & 63;
    const int wid = tid >> 6;
    const long long blockRow = (long long)blockIdx.x * 64;

    const float alpha = alpha_p[0];
    const int lrow = lane & 15;        // fragment row index
    const int cg = (lane >> 4) * 4;    // 4-col group within a 16-col tile
    const int colb = wid * 32;

    // per-thread DyT params for its two column groups
    float4 w4[2], b4[2];
#pragma unroll
    for (int nt = 0; nt < 2; ++nt) {
        const int c = colb + nt * 16 + cg;
        w4[nt] = *reinterpret_cast<const float4*>(&w[c]);
        b4[nt] = *reinterpret_cast<const float4*>(&bias[c]);
    }

    // ---- stage: load x (kept in regs), compute h -> LDS ----
    // fast tanh: tanh(t) = 1 - 2/(1+e^{2t})
    float4 xr[4][2];
#pragma unroll
    for (int mt = 0; mt < 4; ++mt) {
#pragma unroll
        for (int nt = 0; nt < 2; ++nt) {
            const int row = mt * 16 + lrow;
            const int col = colb + nt * 16 + cg;
            const float4 xv =
                *reinterpret_cast<const float4*>(&x[(blockRow + row) * SIZE + col]);
            xr[mt][nt] = xv;
            ushort4 hq;
            float ax, th;
            ax = alpha * xv.x;
            th = 1.0f - __fdividef(2.0f, 1.0f + __expf(2.0f * ax));
            hq.x = f2bf(th * w4[nt].x + b4[nt].x);
            ax = alpha * xv.y;
            th = 1.0f - __fdividef(2.0f, 1.0f + __expf(2.0f * ax));
            hq.y = f2bf(th * w4[nt].y + b4[nt].y);
            ax = alpha * xv.z;
            th = 1.0f - __fdividef(2.0f, 1.0f + __expf(2.0f * ax));
            hq.z = f2bf(th * w4[nt].z + b4[nt].z);
            ax = alpha * xv.w;
            th = 1.0f - __fdividef(2.0f, 1.0f + __expf(2.0f * ax));
            hq.w = f2bf(th * w4[nt].w + b4[nt].w);
            *reinterpret_cast<ushort4*>(&hA[row][col]) = hq;
        }
    }

    // ---- G fragments (used as the M-side operand), L2-resident 32 KB ----
    short8 gf[2][4];
#pragma unroll
    for (int nt = 0; nt < 2; ++nt) {
        const int n = colb + nt * 16 + lrow;
#pragma unroll
        for (int kt = 0; kt < 4; ++kt) {
            gf[nt][kt] = *reinterpret_cast<const short8*>(
                &Gt[n * SIZE + kt * 32 + (lane >> 4) * 8]);
        }
    }

    __syncthreads();

    // ---- MFMA (operands swapped): D[i][j], i = out col (regs), j = out row ----
    f32x4 acc[4][2];
#pragma unroll
    for (int mt = 0; mt < 4; ++mt) {
        short8 hf[4];
#pragma unroll
        for (int kt = 0; kt < 4; ++kt) {
            hf[kt] = *reinterpret_cast<const short8*>(
                &hA[mt * 16 + lrow][kt * 32 + (lane >> 4) * 8]);
        }
#pragma unroll
        for (int nt = 0; nt < 2; ++nt) {
            f32x4 a = {0.f, 0.f, 0.f, 0.f};
#pragma unroll
            for (int kt = 0; kt < 4; ++kt) {
                a = __builtin_amdgcn_mfma_f32_16x16x32_bf16(gf[nt][kt], hf[kt], a,
                                                            0, 0, 0);
            }
            acc[mt][nt] = a;
        }
    }

    // ---- epilogue: float4 store, residual from registers ----
#pragma unroll
    for (int mt = 0; mt < 4; ++mt) {
#pragma unroll
        for (int nt = 0; nt < 2; ++nt) {
            const int row = mt * 16 + lrow;
            const int col = colb + nt * 16 + cg;
            float4 r;
            r.x = acc[mt][nt][0] + xr[mt][nt].x;
            r.y = acc[mt][nt][1] + xr[mt][nt].y;
            r.z = acc[mt][nt][2] + xr[mt][nt].z;
            r.w = acc[mt][nt][3] + xr[mt][nt].w;
            *reinterpret_cast<float4*>(&out[(blockRow + row) * SIZE + col]) = r;
        }
    }
}

extern "C" void kernel_launch(void* const* d_in, const int* in_sizes, int n_in,
                              void* d_out, int out_size, void* d_ws, size_t ws_size,
                              hipStream_t stream) {
    const float* x = (const float*)d_in[0];
    const float* alpha = (const float*)d_in[1];
    const float* dyt_w = (const float*)d_in[2];
    const float* dyt_b = (const float*)d_in[3];
    // d_in[4] = a_real, d_in[5] = a_imag, d_in[8] = ffn_bias: dead code in reference
    const float* b_real = (const float*)d_in[6];
    const float* b_imag = (const float*)d_in[7];
    float* out = (float*)d_out;
    unsigned short* Gt = (unsigned short*)d_ws;  // 128*128 bf16 = 32 KB

    build_gt<<<1, 128, 0, stream>>>(b_real, b_imag, Gt);

    const int rows = out_size / SIZE;       // 32*8192 = 262144
    const int nblocks = rows / 64;          // 4096
    fourier_main<<<nblocks, 256, 0, stream>>>(x, alpha, dyt_w, dyt_b, Gt, out);
}

// Round 5
// 73.124 us; speedup vs baseline: 1.4683x; 1.0049x over previous
//
#include <hip/hip_runtime.h>

#define SIZE 128
#define T_PER_BLK 8   // tiles (64 rows each) per block: 4096/8 = 512 blocks = 2/CU exact

typedef short short8 __attribute__((ext_vector_type(8)));
typedef float f32x4 __attribute__((ext_vector_type(4)));

__device__ __forceinline__ unsigned short f2bf(float f) {
    unsigned int u = __float_as_uint(f);
    unsigned int r = u + 0x7FFFu + ((u >> 16) & 1u);
    return (unsigned short)(r >> 16);
}

// Build Gt[n][k] = gr[(n-k) & 127] in bf16, gr = Re(ifft(b)). Packed u32 stores.
__global__ void build_gt(const float* __restrict__ br, const float* __restrict__ bi,
                         unsigned int* __restrict__ Gt) {
    __shared__ float gr[SIZE];
    const int t = threadIdx.x;  // 0..127
    float acc = 0.0f;
    for (int j = 0; j < SIZE; ++j) {
        int p = (j * t) & 127;                 // exact periodic reduction
        float a = (float)p * (1.0f / 64.0f);   // angle in units of pi
        acc += br[j] * cospif(a) - bi[j] * sinpif(a);
    }
    gr[t] = acc * (1.0f / 128.0f);
    __syncthreads();
    for (int k2 = 0; k2 < 64; ++k2) {
        unsigned int lo = f2bf(gr[(t - 2 * k2) & 127]);
        unsigned int hi = f2bf(gr[(t - 2 * k2 - 1) & 127]);
        Gt[t * 64 + k2] = lo | (hi << 16);
    }
}

// out[m][n] = sum_k h[m][k]*Gt[n][k] + x[m][n], h = tanh(alpha*x)*w + bias.
// 256 threads / 4 waves; wave w owns cols [32w,32w+32). 8 tiles per block,
// double-buffered LDS h, 1 barrier/tile, x prefetched 1 tile ahead in regs.
__global__ __launch_bounds__(256, 3) void fourier_main(
    const float* __restrict__ x, const float* __restrict__ alpha_p,
    const float* __restrict__ w, const float* __restrict__ bias,
    const unsigned short* __restrict__ Gt, float* __restrict__ out) {
    __shared__ unsigned short hA[2][64][136];  // +8 pad breaks pow2 stride

    const int tid = threadIdx.x;
    const int lane = tid & 63;
    const int wid = tid >> 6;
    const int lrow = lane & 15;      // fragment row
    const int slot = lane >> 4;      // k-chunk / col-group selector
    const int cg = slot * 4;
    const int colb = wid * 32;

    const float a2 = 2.0f * alpha_p[0];

    // per-thread DyT params for its two column groups
    float4 w4[2], b4[2];
#pragma unroll
    for (int nt = 0; nt < 2; ++nt) {
        const int c = colb + nt * 16 + cg;
        w4[nt] = *reinterpret_cast<const float4*>(&w[c]);
        b4[nt] = *reinterpret_cast<const float4*>(&bias[c]);
    }

    // G fragments: loaded ONCE per block (L2-resident), reused for 8 tiles
    short8 gf[2][4];
#pragma unroll
    for (int nt = 0; nt < 2; ++nt) {
        const int n = colb + nt * 16 + lrow;
#pragma unroll
        for (int kt = 0; kt < 4; ++kt) {
            gf[nt][kt] = *reinterpret_cast<const short8*>(
                &Gt[n * SIZE + kt * 32 + slot * 8]);
        }
    }

    // 32-bit element offsets (max 33.5M < 2^31)
    const unsigned tile0 = (unsigned)blockIdx.x * (T_PER_BLK * 64u * SIZE);
    unsigned soff[4][2];  // thread's static (row,col) footprint within a tile
#pragma unroll
    for (int mt = 0; mt < 4; ++mt)
#pragma unroll
        for (int nt = 0; nt < 2; ++nt)
            soff[mt][nt] = (mt * 16 + lrow) * SIZE + colb + nt * 16 + cg;

    float4 xA[4][2], xB[4][2];

    // DyT pipeline stage: fp32 x -> bf16 h (packed ushort4)
    auto hquad = [&](const float4 xv, int nt) -> ushort4 {
        ushort4 hq;
        float t, e, r, th;
        t = a2 * xv.x; e = __expf(t); r = __builtin_amdgcn_rcpf(1.0f + e);
        th = fmaf(-2.0f, r, 1.0f); hq.x = f2bf(fmaf(th, w4[nt].x, b4[nt].x));
        t = a2 * xv.y; e = __expf(t); r = __builtin_amdgcn_rcpf(1.0f + e);
        th = fmaf(-2.0f, r, 1.0f); hq.y = f2bf(fmaf(th, w4[nt].y, b4[nt].y));
        t = a2 * xv.z; e = __expf(t); r = __builtin_amdgcn_rcpf(1.0f + e);
        th = fmaf(-2.0f, r, 1.0f); hq.z = f2bf(fmaf(th, w4[nt].z, b4[nt].z));
        t = a2 * xv.w; e = __expf(t); r = __builtin_amdgcn_rcpf(1.0f + e);
        th = fmaf(-2.0f, r, 1.0f); hq.w = f2bf(fmaf(th, w4[nt].w, b4[nt].w));
        return hq;
    };

    // ---- prologue: tile 0 -> xA, h(0) -> buf 0 ----
#pragma unroll
    for (int mt = 0; mt < 4; ++mt)
#pragma unroll
        for (int nt = 0; nt < 2; ++nt)
            xA[mt][nt] = *reinterpret_cast<const float4*>(&x[tile0 + soff[mt][nt]]);
#pragma unroll
    for (int mt = 0; mt < 4; ++mt)
#pragma unroll
        for (int nt = 0; nt < 2; ++nt)
            *reinterpret_cast<ushort4*>(
                &hA[0][mt * 16 + lrow][colb + nt * 16 + cg]) = hquad(xA[mt][nt], nt);
    __syncthreads();

    // ---- pipelined tile loop: body(t) reads buf pp, writes buf pp^1 ----
    auto body = [&](int tt, float4 (&xc)[4][2], float4 (&xn)[4][2], int pp)
        __attribute__((always_inline)) {
        const unsigned tbase = tile0 + (unsigned)tt * (64u * SIZE);
        const bool pf = (tt + 1) < T_PER_BLK;

        // 1. prefetch next tile's x (latency hidden under MFMA + this barrier)
        if (pf) {
#pragma unroll
            for (int mt = 0; mt < 4; ++mt)
#pragma unroll
                for (int nt = 0; nt < 2; ++nt)
                    xn[mt][nt] = *reinterpret_cast<const float4*>(
                        &x[tbase + 64u * SIZE + soff[mt][nt]]);
        }

        // 2. MFMA on current buffer. Swapped operands: acc regs = 4 output cols.
        f32x4 acc[4][2];
#pragma unroll
        for (int mt = 0; mt < 4; ++mt) {
            short8 hf[4];
#pragma unroll
            for (int kt = 0; kt < 4; ++kt)
                hf[kt] = *reinterpret_cast<const short8*>(
                    &hA[pp][mt * 16 + lrow][kt * 32 + slot * 8]);
#pragma unroll
            for (int nt = 0; nt < 2; ++nt) {
                f32x4 a = {0.f, 0.f, 0.f, 0.f};
#pragma unroll
                for (int kt = 0; kt < 4; ++kt)
                    a = __builtin_amdgcn_mfma_f32_16x16x32_bf16(gf[nt][kt], hf[kt],
                                                                a, 0, 0, 0);
                acc[mt][nt] = a;
            }
        }

        // 3. h(t+1) -> other buffer (no hazard: different buffer than step-2 reads)
        if (pf) {
#pragma unroll
            for (int mt = 0; mt < 4; ++mt)
#pragma unroll
                for (int nt = 0; nt < 2; ++nt)
                    *reinterpret_cast<ushort4*>(
                        &hA[pp ^ 1][mt * 16 + lrow][colb + nt * 16 + cg]) =
                        hquad(xn[mt][nt], nt);
        }

        // 4. epilogue: nontemporal float4 stores (don't thrash L3's copy of x)
#pragma unroll
        for (int mt = 0; mt < 4; ++mt)
#pragma unroll
            for (int nt = 0; nt < 2; ++nt) {
                f32x4 r;
                r[0] = acc[mt][nt][0] + xc[mt][nt].x;
                r[1] = acc[mt][nt][1] + xc[mt][nt].y;
                r[2] = acc[mt][nt][2] + xc[mt][nt].z;
                r[3] = acc[mt][nt][3] + xc[mt][nt].w;
                __builtin_nontemporal_store(
                    r, reinterpret_cast<f32x4*>(&out[tbase + soff[mt][nt]]));
            }

        // 5. one barrier/tile: publishes buf pp^1, retires all reads of buf pp
        if (pf) __syncthreads();
    };

#pragma unroll
    for (int t = 0; t < T_PER_BLK; t += 2) {
        body(t, xA, xB, 0);
        body(t + 1, xB, xA, 1);
    }
}

extern "C" void kernel_launch(void* const* d_in, const int* in_sizes, int n_in,
                              void* d_out, int out_size, void* d_ws, size_t ws_size,
                              hipStream_t stream) {
    const float* x = (const float*)d_in[0];
    const float* alpha = (const float*)d_in[1];
    const float* dyt_w = (const float*)d_in[2];
    const float* dyt_b = (const float*)d_in[3];
    // d_in[4] = a_real, d_in[5] = a_imag, d_in[8] = ffn_bias: dead code in reference
    const float* b_real = (const float*)d_in[6];
    const float* b_imag = (const float*)d_in[7];
    float* out = (float*)d_out;

    build_gt<<<1, 128, 0, stream>>>(b_real, b_imag, (unsigned int*)d_ws);

    const int rows = out_size / SIZE;                 // 262144
    const int nblocks = rows / (64 * T_PER_BLK);      // 512
    fourier_main<<<nblocks, 256, 0, stream>>>(x, alpha, dyt_w, dyt_b,
                                              (const unsigned short*)d_ws, out);
}